// Round 13
// baseline (898.510 us; speedup 1.0000x reference)
//
#include <hip/hip_runtime.h>
#include <cfloat>

typedef unsigned long long ull;

// Problem constants (match reference setup_inputs)
constexpr int NB = 8, NN = 3000, NM = 3000, KK = 8;
constexpr int CAP = 48;                       // per-row/col sparse capacity (padded)
constexpr float SCALE   = 14.426950408889634f;   // 1/(EPS*ln2), EPS=0.1
constexpr float UNSCALE = 0.06931471805599453f;  // EPS*ln2
constexpr float THRESH  = 0.1f;
constexpr unsigned DUMMY_PAT = 0x7f7f7f7fu;   // memset pattern: val=3.39e38 -> exp2()==0
constexpr int NCH = 16;                       // coltop chunks (<=188 rows each)

// Sinkhorn geometry (R10/R12-validated): 8 blocks/batch, TPB=512 -> 2 waves/
// SIMD at 1 block/CU -> 256 VGPR budget (124 used, NO spill — R11's TPB=1024
// halved the budget to 128 and spilled the persistent pk arrays to scratch).
constexpr int BPB  = 8;
constexpr int NBLK = NB * BPB;                // 64 blocks
constexpr int TPB  = 512;                     // 8 waves
constexpr int RPB  = NN / BPB;                // 375 rows per block

#if __has_builtin(__builtin_amdgcn_exp2f)
#define FEXP2(x) __builtin_amdgcn_exp2f(x)
#else
#define FEXP2(x) exp2f(x)
#endif
#if __has_builtin(__builtin_amdgcn_logf)
#define FLOG2(x) __builtin_amdgcn_logf(x)   // v_log_f32 = log2
#else
#define FLOG2(x) __log2f(x)
#endif

// Relaxed agent-scope 64-bit atomics: plain coherence-point accesses, NO cache
// flushes (acquire/release at agent scope emit buffer_inv/buffer_wbl2 — the R2
// disaster). 64-bit units carry (tag<<32)|value so publication is in-band.
__device__ __forceinline__ ull aload64(const ull* p) {
  return __hip_atomic_load(p, __ATOMIC_RELAXED, __HIP_MEMORY_SCOPE_AGENT);
}
__device__ __forceinline__ void astore64(ull* p, ull x) {
  __hip_atomic_store(p, x, __ATOMIC_RELAXED, __HIP_MEMORY_SCOPE_AGENT);
}

// Pull one producer slice (RPB=375 tagged ulls) into LDS. Batched first
// attempt (6 independent loads in one MALL latency window), re-poll stragglers.
__device__ __forceinline__ void pull_tagged(const ull* __restrict__ src, int tag,
                                            float* __restrict__ dst, int lane) {
  const int nfull = RPB - 5 * 64;             // 55: lanes < 55 own 6 elements
  unsigned pend = (lane < nfull) ? 0x3Fu : 0x1Fu;
  {
    ull x0 = aload64(&src[lane]);
    ull x1 = aload64(&src[lane + 64]);
    ull x2 = aload64(&src[lane + 128]);
    ull x3 = aload64(&src[lane + 192]);
    ull x4 = aload64(&src[lane + 256]);
    ull x5 = (lane < nfull) ? aload64(&src[lane + 320]) : 0;
    if ((int)(x0 >> 32) == tag) { dst[lane]       = __uint_as_float((unsigned)x0); pend &= ~1u;  }
    if ((int)(x1 >> 32) == tag) { dst[lane + 64]  = __uint_as_float((unsigned)x1); pend &= ~2u;  }
    if ((int)(x2 >> 32) == tag) { dst[lane + 128] = __uint_as_float((unsigned)x2); pend &= ~4u;  }
    if ((int)(x3 >> 32) == tag) { dst[lane + 192] = __uint_as_float((unsigned)x3); pend &= ~8u;  }
    if ((int)(x4 >> 32) == tag) { dst[lane + 256] = __uint_as_float((unsigned)x4); pend &= ~16u; }
    if ((lane < nfull) && (int)(x5 >> 32) == tag) { dst[lane + 320] = __uint_as_float((unsigned)x5); pend &= ~32u; }
  }
  while (pend) {
    __builtin_amdgcn_s_sleep(1);
#pragma unroll
    for (int j = 0; j < 6; ++j) {
      if (!((pend >> j) & 1u)) continue;
      ull x = aload64(&src[lane + 64 * j]);
      if ((int)(x >> 32) == tag) {
        dst[lane + 64 * j] = __uint_as_float((unsigned)x);
        pend &= ~(1u << j);
      }
    }
  }
}

// ---------------------------------------------------------------------------
// K1: row L2 norms (as inverse) + top-8 smallest per row, VALUES kept.
// 8 rows/block, 32 lanes/row; register top-8 + 5-round shfl_xor bitonic merge.
// Writes rowsel (for extras dup-checks) AND the r_pk base slots 0..7 directly
// (fused base fill — value chain (C*inv)*SCALE identical to prior rounds).
// ---------------------------------------------------------------------------
__global__ __launch_bounds__(256) void k_rowprep(const float* __restrict__ C,
                                                 float* __restrict__ invnorms,
                                                 int2* __restrict__ rowsel,
                                                 int2* __restrict__ r_pk) {
  const int bn = blockIdx.x * 8 + (threadIdx.x >> 5);   // row id, 8 per block
  const int l  = threadIdx.x & 31;
  const float4* row4 = reinterpret_cast<const float4*>(C + (size_t)bn * NM);

  float tv[8]; int ti[8];
#pragma unroll
  for (int q = 0; q < 8; ++q) { tv[q] = FLT_MAX; ti[q] = 0x7fffffff; }
  float sq = 0.f;
  for (int c = 0; c < 24; ++c) {              // 750 float4 / 32 lanes
    int i = l + 32 * c;
    if (i < NM / 4) {
      float4 f = row4[i];
      sq += f.x * f.x + f.y * f.y + f.z * f.z + f.w * f.w;
      float e[4] = { f.x, f.y, f.z, f.w };
#pragma unroll
      for (int j = 0; j < 4; ++j) {
        float v = e[j];
        if (v < tv[7]) {                      // stable: strict <, asc indices
          int idx = 4 * i + j;
          int pos = 8;
#pragma unroll
          for (int q = 7; q >= 0; --q) if (v < tv[q]) pos = q;
#pragma unroll
          for (int q = 7; q >= 1; --q) if (q > pos) { tv[q] = tv[q-1]; ti[q] = ti[q-1]; }
#pragma unroll
          for (int q = 0; q < 8; ++q) if (q == pos) { tv[q] = v; ti[q] = idx; }
        }
      }
    }
  }
#pragma unroll
  for (int o = 16; o; o >>= 1) sq += __shfl_down(sq, o, 32);

#pragma unroll
  for (int msk = 1; msk <= 16; msk <<= 1) {
    float pv[8]; int pi[8];
#pragma unroll
    for (int q = 0; q < 8; ++q) { pv[q] = __shfl_xor(tv[q], msk); pi[q] = __shfl_xor(ti[q], msk); }
    float mv[8]; int mi[8];
#pragma unroll
    for (int q = 0; q < 8; ++q) {             // min with reversed partner
      float av = tv[q], bv = pv[7 - q];
      int   ai = ti[q], bi = pi[7 - q];
      bool ta = (av < bv) || (av == bv && ai < bi);
      mv[q] = ta ? av : bv; mi[q] = ta ? ai : bi;
    }
    auto ce = [&](int i, int j) {             // compare-exchange (val,idx) lex
      bool sw = (mv[i] > mv[j]) || (mv[i] == mv[j] && mi[i] > mi[j]);
      float fv = sw ? mv[j] : mv[i], gv = sw ? mv[i] : mv[j];
      int   fi = sw ? mi[j] : mi[i], gi = sw ? mi[i] : mi[j];
      mv[i] = fv; mv[j] = gv; mi[i] = fi; mi[j] = gi;
    };
    ce(0,4); ce(1,5); ce(2,6); ce(3,7);       // bitonic 3-stage cleaner
    ce(0,2); ce(1,3); ce(4,6); ce(5,7);
    ce(0,1); ce(2,3); ce(4,5); ce(6,7);
#pragma unroll
    for (int q = 0; q < 8; ++q) { tv[q] = mv[q]; ti[q] = mi[q]; }
  }

  if (l == 0) {
    float nm = sqrtf(sq);
    float inv = 1.0f / fmaxf(nm, 1e-12f);
    invnorms[bn] = inv;
#pragma unroll
    for (int q = 0; q < 8; ++q) {
      rowsel[(size_t)bn * KK + q] = make_int2(ti[q], __float_as_int(tv[q]));
      float v2 = tv[q] * inv * SCALE;         // == fill's (C*inv)*SCALE chain
      r_pk[(size_t)bn * CAP + q] = make_int2(ti[q], __float_as_int(v2));
    }
  }
}

// ---------------------------------------------------------------------------
// K2a: column top-8, phase 1. NO LDS, no syncthreads: each wave owns one
// <=188-row chunk; lane owns 4 columns via float4 (1 KB/row/wave contiguous).
// key = (valbits<<32) | ~n : single u64 compare == (val desc, n asc).
// ---------------------------------------------------------------------------
__global__ __launch_bounds__(256) void k_coltop1(const float* __restrict__ C,
                                                 const float* __restrict__ invnorms,
                                                 ull* __restrict__ partial) {
  const int b = blockIdx.z, rc = blockIdx.y, cg = blockIdx.x;
  const int tid = threadIdx.x;
  const int w = tid >> 6, l = tid & 63;
  const int g4 = cg * 64 + l;                 // float4 group, valid < 750
  const int chunk = rc * 4 + w;               // 0..15

  ull tv[4][8];
#pragma unroll
  for (int j = 0; j < 4; ++j)
#pragma unroll
    for (int q = 0; q < 8; ++q) tv[j][q] = 0;   // real keys always > 0

  if (g4 < NM / 4) {
    const int base_r = rc * 750;
    const int r0 = base_r + w * 188;
    const int r1 = min(base_r + 750, r0 + 188);
    const float4* base = reinterpret_cast<const float4*>(
        C + (size_t)b * NN * NM) + g4;
    const float* ivn = invnorms + (size_t)b * NN;
    for (int n = r0; n < r1; ++n) {
      float4 f = base[(size_t)n * (NM / 4)];
      float iv = ivn[n];                      // wave-uniform -> scalar load
      float e[4] = { f.x * iv, f.y * iv, f.z * iv, f.w * iv };
      ull lo = (ull)(unsigned)~n;
#pragma unroll
      for (int j = 0; j < 4; ++j) {
        ull key = ((ull)__float_as_uint(e[j]) << 32) | lo;
        if (key > tv[j][7]) {
          int pos = 8;
#pragma unroll
          for (int q = 7; q >= 0; --q) if (key > tv[j][q]) pos = q;
#pragma unroll
          for (int q = 7; q >= 1; --q) if (q > pos) tv[j][q] = tv[j][q-1];
#pragma unroll
          for (int q = 0; q < 8; ++q) if (q == pos) tv[j][q] = key;
        }
      }
    }
    ull* dst = partial + (((size_t)b * NCH + chunk) * NM + (size_t)4 * g4) * 8;
#pragma unroll
    for (int j = 0; j < 4; ++j)
#pragma unroll
      for (int q = 0; q < 8; ++q) dst[j * 8 + q] = tv[j][q];
  }
}

// ---------------------------------------------------------------------------
// K2b: column top-8, phase 2. 64-thread blocks (375 blocks) stream 16 sorted
// chunk-lists (64 B coalesced, early-break) into a register top-8. Writes
// colsel (for extras dup-checks) AND the c_pk base slots 0..7 directly.
// ---------------------------------------------------------------------------
__global__ __launch_bounds__(64) void k_coltop2(const ull* __restrict__ partial,
                                                int2* __restrict__ colsel,
                                                int2* __restrict__ c_pk) {
  int t = blockIdx.x * 64 + threadIdx.x;      // b*NM + m
  if (t >= NB * NM) return;
  int b = t / NM, m = t % NM;
  ull top[8];
#pragma unroll
  for (int q = 0; q < 8; ++q) top[q] = 0;
  for (int c = 0; c < NCH; ++c) {
    const ull* src = partial + (((size_t)b * NCH + c) * NM + m) * 8;
    ull buf[8];
#pragma unroll
    for (int q = 0; q < 8; ++q) buf[q] = src[q];
    for (int q = 0; q < 8; ++q) {
      ull key = buf[q];
      if (key <= top[7]) break;               // list sorted desc -> rest smaller
      int pos = 8;
#pragma unroll
      for (int z = 7; z >= 0; --z) if (key > top[z]) pos = z;
#pragma unroll
      for (int z = 7; z >= 1; --z) if (z > pos) top[z] = top[z-1];
#pragma unroll
      for (int z = 0; z < 8; ++z) if (z == pos) top[z] = key;
    }
  }
#pragma unroll
  for (int q = 0; q < 8; ++q) {
    int n = (int)~(unsigned)top[q];
    int vb = (int)(top[q] >> 32);             // (C*inv) bits
    colsel[(size_t)t * KK + q] = make_int2(n, vb);
    float v2 = __int_as_float(vb) * SCALE;    // == fill's chain
    c_pk[(size_t)t * CAP + q] = make_int2(n, __float_as_int(v2));
  }
}

// ---------------------------------------------------------------------------
// K3 (extras only): non-duplicate appends to slots 8+. Base slots were
// written by k_rowprep/k_coltop2; pk arrays pre-filled with DUMMY_PAT.
// ---------------------------------------------------------------------------
__global__ __launch_bounds__(256) void k_extras(const float* __restrict__ invnorms,
    const int2* __restrict__ rowsel, const int2* __restrict__ colsel,
    int* r_cnt, int* c_cnt, int2* __restrict__ r_pk, int2* __restrict__ c_pk) {
  int t = blockIdx.x * 256 + threadIdx.x;
  if (t >= NB * NN * KK) return;
  int bn = t / KK;
  int b = bn / NN; int n = bn % NN;
  float inv_bn = invnorms[bn];
  int2 rs = rowsel[t];                        // (m, raw C bits)
  int2 cs = colsel[t];                        // (n2, (C*inv) bits)
  int m = n;                                  // extras: t = (b*NM+m)*KK + k
  {  // colsel entry (b,m,k): row n3 gains column m unless duplicate
    int n3 = cs.x;
    const int2* rl = rowsel + ((size_t)b * NN + n3) * KK;
    bool dup = false;
#pragma unroll
    for (int q = 0; q < KK; ++q) dup |= (rl[q].x == m);
    if (!dup) {
      int slot = 8 + atomicAdd(&r_cnt[(size_t)b * NN + n3], 1);
      if (slot < CAP) {
        float v2 = __int_as_float(cs.y) * SCALE;
        r_pk[((size_t)b * NN + n3) * CAP + slot] = make_int2(m, __float_as_int(v2));
      }
    }
  }
  {  // rowsel entry (b,n,k): column mm gains row n unless duplicate
    int mm = rs.x;
    const int2* cl = colsel + ((size_t)b * NM + mm) * KK;
    bool dup = false;
#pragma unroll
    for (int q = 0; q < KK; ++q) dup |= (cl[q].x == n);
    if (!dup) {
      int slot = 8 + atomicAdd(&c_cnt[(size_t)b * NM + mm], 1);
      if (slot < CAP) {
        float v2 = __int_as_float(rs.y) * inv_bn * SCALE;
        c_pk[((size_t)b * NM + mm) * CAP + slot] = make_int2(n, __float_as_int(v2));
      }
    }
  }
}

// ---------------------------------------------------------------------------
// K5: tagged pull-as-ready sparse Sinkhorn (R9/R12-validated, BPB=8 TPB=512).
// Values published as (tag<<32)|bits via relaxed 64-bit agent atomics into
// parity buffers; consumers poll the data itself. Own slice registers->LDS.
// Reuse-distance-2 => pollers only ever see stale tags, never future ones.
// Final reduction folded in: blocks publish tagged costparts; block 0 polls
// all 64 and writes out[0] (fixed order, identical to the old k_final2).
// ---------------------------------------------------------------------------
__global__ __launch_bounds__(TPB, 1) void k_sink_coop(
    const float* __restrict__ mu, const float* __restrict__ nu,
    const int2* __restrict__ r_pk, const int2* __restrict__ c_pk,
    ull* __restrict__ Upub, ull* __restrict__ Vpub,
    ull* errW, ull* costW, float* __restrict__ out) {
  const int blk = blockIdx.x;
  const int b = blk % NB, slice = blk / NB;
  const int tid = threadIdx.x;
  const int w = tid >> 6, lane = tid & 63;
  const int r = slice * RPB + tid;
  const bool has_r = (tid < RPB);             // NN == NM: same geometry

  // wave-resident sparse entries (persistent VGPRs; 124 VGPR total, no spill)
  float rval[CAP], cval[CAP];
  unsigned ridx[CAP / 2], cidx[CAP / 2];
  float u = 0.f, vv = 0.f, lmu = 0.f, lnu = 0.f;
  if (has_r) {
    const int2* rp = r_pk + ((size_t)b * NN + r) * CAP;
    const int2* cp = c_pk + ((size_t)b * NM + r) * CAP;
#pragma unroll
    for (int i = 0; i < CAP; i += 2) {
      int2 e0 = rp[i], e1 = rp[i + 1];
      rval[i] = __int_as_float(e0.y); rval[i + 1] = __int_as_float(e1.y);
      unsigned i0 = min((unsigned)e0.x & 0xFFFFu, (unsigned)(NN - 1));  // clamp dummies
      unsigned i1 = min((unsigned)e1.x & 0xFFFFu, (unsigned)(NN - 1));
      ridx[i / 2] = i0 | (i1 << 16);
      int2 f0 = cp[i], f1 = cp[i + 1];
      cval[i] = __int_as_float(f0.y); cval[i + 1] = __int_as_float(f1.y);
      unsigned j0 = min((unsigned)f0.x & 0xFFFFu, (unsigned)(NN - 1));
      unsigned j1 = min((unsigned)f1.x & 0xFFFFu, (unsigned)(NN - 1));
      cidx[i / 2] = j0 | (j1 << 16);
    }
    lmu = FLOG2(mu[(size_t)b * NN + r] + 1e-8f);
    lnu = FLOG2(nu[(size_t)b * NM + r] + 1e-8f);
  }

  __shared__ float XL[NN];                    // staged U or V (12 KB)
  __shared__ float sred[TPB / 64];
  __shared__ float errl[BPB];
  int itf = 0;
  bool done = false;

  for (int it = 0; it < 100; ++it) {
    // ---- stage-A: XL <- V(it-1) (zeros at it==0); own slice from registers ----
    if (it == 0) {
      for (int i = tid; i < NN; i += TPB) XL[i] = 0.f;
    } else {
      if (has_r) XL[r] = vv;
      if (w != slice) {
        const ull* src = Vpub + (size_t)((it - 1) & 1) * (NB * NN)
                       + (size_t)b * NN + (size_t)w * RPB;
        pull_tagged(src, it, XL + w * RPB, lane);
      }
    }
    __syncthreads();

    // ---- compute-A: u update, publish tagged U ----
    float errp = 0.f;
    if (has_r) {
      float s = 0.f;
#pragma unroll
      for (int i = 0; i < CAP; ++i) {
        int ix = (ridx[i >> 1] >> ((i & 1) * 16)) & 0xFFFF;
        s += FEXP2(u + XL[ix] - rval[i]);
      }
      float un = lmu - FLOG2(1e-8f + s) + u;
      errp = fabsf(un - u);
      u = un;
      astore64(&Upub[(size_t)(it & 1) * (NB * NN) + (size_t)b * NN + r],
               ((ull)(unsigned)(it + 1) << 32) | __float_as_uint(u));
    }
#pragma unroll
    for (int o = 32; o; o >>= 1) errp += __shfl_down(errp, o);
    if (lane == 0) sred[w] = errp;
    __syncthreads();                          // also: XL(V) reads done -> safe to overwrite
    if (tid == 0) {
      float e = sred[0] + sred[1] + sred[2] + sred[3]
              + sred[4] + sred[5] + sred[6] + sred[7];
      astore64(&errW[(size_t)((it & 1) * NB + b) * BPB * 16 + slice * 16],
               ((ull)(unsigned)(it + 1) << 32) | __float_as_uint(e));
      errl[slice] = e;
    }

    // ---- stage-B: XL <- U(it); own slice from registers; err words ----
    if (has_r) XL[r] = u;
    if (w != slice) {
      const ull* src = Upub + (size_t)(it & 1) * (NB * NN)
                     + (size_t)b * NN + (size_t)w * RPB;
      pull_tagged(src, it + 1, XL + w * RPB, lane);
      if (lane == 0) {
        const ull* ep = errW + (size_t)((it & 1) * NB + b) * BPB * 16 + w * 16;
        ull x = aload64(ep);
        while ((int)(x >> 32) != it + 1) { __builtin_amdgcn_s_sleep(1); x = aload64(ep); }
        errl[w] = __uint_as_float((unsigned)x);
      }
    }
    __syncthreads();

    // ---- compute-B: uniform done decision, v update, publish tagged V ----
    float errtot = errl[0] + errl[1] + errl[2] + errl[3]
                 + errl[4] + errl[5] + errl[6] + errl[7];   // fixed order
    done = (errtot * UNSCALE < THRESH);
    if (has_r) {
      float s = 0.f;
#pragma unroll
      for (int i = 0; i < CAP; ++i) {
        int ix = (cidx[i >> 1] >> ((i & 1) * 16)) & 0xFFFF;
        s += FEXP2(vv + XL[ix] - cval[i]);
      }
      vv = lnu - FLOG2(1e-8f + s) + vv;
      astore64(&Vpub[(size_t)(it & 1) * (NB * NN) + (size_t)b * NN + r],
               ((ull)(unsigned)(it + 1) << 32) | __float_as_uint(vv));
    }
    __syncthreads();                          // XL(U) reads done -> next overwrite safe
    itf = it;
    if (done) break;                          // uniform across the batch
  }

  // ---- epilogue: XL <- V(itf); cost partial over own rows ----
  if (has_r) XL[r] = vv;
  if (w != slice) {
    const ull* src = Vpub + (size_t)(itf & 1) * (NB * NN)
                   + (size_t)b * NN + (size_t)w * RPB;
    pull_tagged(src, itf + 1, XL + w * RPB, lane);
  }
  __syncthreads();
  float cs = 0.f;
  if (has_r) {
#pragma unroll
    for (int i = 0; i < CAP; ++i) {
      int ix = (ridx[i >> 1] >> ((i & 1) * 16)) & 0xFFFF;
      float val = rval[i];
      cs += FEXP2(u + XL[ix] - val) * val;    // dummies give exp2(-huge)*big = 0
    }
  }
#pragma unroll
  for (int o = 32; o; o >>= 1) cs += __shfl_down(cs, o);
  if (lane == 0) sred[w] = cs;
  __syncthreads();
  if (tid == 0) {
    float tot = sred[0] + sred[1] + sred[2] + sred[3]
              + sred[4] + sred[5] + sred[6] + sred[7];
    astore64(&costW[b * BPB + slice], (1ull << 32) | __float_as_uint(tot));
  }

  // ---- folded final reduction: block 0 polls all 64 tagged costparts ----
  if (blk == 0 && tid == 0) {
    float vals[NB * BPB];
    unsigned pend_hi = 0xFFFFFFFFu, pend_lo = 0xFFFFFFFFu;  // 64 entries
    for (;;) {
      bool all = true;
      for (int i = 0; i < NB * BPB; ++i) {
        unsigned bit = 1u << (i & 31);
        unsigned& pw = (i < 32) ? pend_lo : pend_hi;
        if (!(pw & bit)) continue;
        ull x = aload64(&costW[i]);
        if ((int)(x >> 32) == 1) { vals[i] = __uint_as_float((unsigned)x); pw &= ~bit; }
        else all = false;
      }
      if (all && !pend_lo && !pend_hi) break;
      __builtin_amdgcn_s_sleep(2);
    }
    float tot = 0.f;
    for (int bb = 0; bb < NB; ++bb) {
      float cb = 0.f;
      for (int s = 0; s < BPB; ++s) cb += vals[bb * BPB + s];
      tot += cb * UNSCALE;
    }
    out[0] = tot * (1.0f / NB);
  }
}

// ---------------------------------------------------------------------------
extern "C" void kernel_launch(void* const* d_in, const int* in_sizes, int n_in,
                              void* d_out, int out_size, void* d_ws, size_t ws_size,
                              hipStream_t stream) {
  const float* mu = (const float*)d_in[0];
  const float* nu = (const float*)d_in[1];
  const float* C  = (const float*)d_in[2];
  float* out = (float*)d_out;

  char* ws = (char*)d_ws;
  size_t off = 0;
  auto alloc = [&](size_t bytes) {
    void* p = ws + off;
    off += (bytes + 255) & ~(size_t)255;
    return p;
  };
  float* invnorms = (float*)alloc(sizeof(float) * NB * NN);
  int2*  rowsel   = (int2*) alloc(sizeof(int2)  * NB * NN * KK);     // (m, raw bits)
  int2*  colsel   = (int2*) alloc(sizeof(int2)  * NB * NM * KK);     // (n, scaled bits)
  ull*   partial  = (ull*)  alloc(sizeof(ull)   * NB * NCH * NM * 8); // 24.6 MB
  int2*  r_pk     = (int2*) alloc(sizeof(int2)  * NB * NN * CAP);
  int2*  c_pk     = (int2*) alloc(sizeof(int2)  * NB * NM * CAP);    // contiguous after r_pk
  // ---- zeroed region starts here (tags must reset every launch/replay) ----
  ull*   Upub     = (ull*)  alloc(sizeof(ull)   * 2 * NB * NN);      // tagged parity dbuf
  ull*   Vpub     = (ull*)  alloc(sizeof(ull)   * 2 * NB * NM);
  ull*   errW     = (ull*)  alloc(sizeof(ull)   * 2 * NB * BPB * 16);
  int*   r_cnt    = (int*)  alloc(sizeof(int)   * NB * NN);
  int*   c_cnt    = (int*)  alloc(sizeof(int)   * NB * NM);
  ull*   costW    = (ull*)  alloc(sizeof(ull)   * NB * BPB);         // tagged costparts
  (void)ws_size; (void)in_sizes; (void)n_in; (void)out_size;

  // pk arrays pre-filled with dummy pattern (val=3.39e38, idx clamped in sink)
  hipMemsetD32Async((hipDeviceptr_t)r_pk, (int)DUMMY_PAT,
                    (size_t)2 * NB * NN * CAP * 2, stream);
  size_t span = (size_t)((char*)costW - (char*)Upub)
              + ((sizeof(ull) * NB * BPB + 255) & ~(size_t)255);
  hipMemsetAsync(Upub, 0, span, stream);      // Upub..costW (tags -> 0)

  hipLaunchKernelGGL(k_rowprep, dim3(NB * NN / 8), dim3(256), 0, stream,
                     C, invnorms, rowsel, r_pk);
  hipLaunchKernelGGL(k_coltop1, dim3(12, NCH / 4, NB), dim3(256), 0, stream,
                     C, invnorms, partial);
  hipLaunchKernelGGL(k_coltop2, dim3((NB * NM + 63) / 64), dim3(64), 0, stream,
                     partial, colsel, c_pk);
  int nthreads = NB * NN * KK;
  hipLaunchKernelGGL(k_extras, dim3((nthreads + 255) / 256), dim3(256), 0, stream,
                     invnorms, rowsel, colsel, r_cnt, c_cnt, r_pk, c_pk);

  void* args[] = { (void*)&mu, (void*)&nu, (void*)&r_pk, (void*)&c_pk,
                   (void*)&Upub, (void*)&Vpub, (void*)&errW, (void*)&costW,
                   (void*)&out };
  hipLaunchCooperativeKernel((const void*)k_sink_coop, dim3(NBLK), dim3(TPB),
                             args, 0, stream);
}

// Round 14
// 828.505 us; speedup vs baseline: 1.0845x; 1.0845x over previous
//
#include <hip/hip_runtime.h>
#include <cfloat>

typedef unsigned long long ull;

// Problem constants (match reference setup_inputs)
constexpr int NB = 8, NN = 3000, NM = 3000, KK = 8;
constexpr int CAP = 48;                       // per-row/col sparse capacity (padded)
constexpr float SCALE   = 14.426950408889634f;   // 1/(EPS*ln2), EPS=0.1
constexpr float UNSCALE = 0.06931471805599453f;  // EPS*ln2
constexpr float THRESH  = 0.1f;
constexpr unsigned DUMMY_PAT = 0x7f7f7f7fu;   // memset pattern: val=3.39e38 -> exp2()==0
constexpr int NCH = 32;                       // coltop chunks (94/93 rows each)

// Sinkhorn geometry (R10/R12-validated): 8 blocks/batch, TPB=512 -> 2 waves/
// SIMD at 1 block/CU -> 256 VGPR budget (124 used, NO spill — R11's TPB=1024
// halved the budget to 128 and spilled the persistent pk arrays to scratch).
constexpr int BPB  = 8;
constexpr int NBLK = NB * BPB;                // 64 blocks
constexpr int TPB  = 512;                     // 8 waves
constexpr int RPB  = NN / BPB;                // 375 rows per block

#if __has_builtin(__builtin_amdgcn_exp2f)
#define FEXP2(x) __builtin_amdgcn_exp2f(x)
#else
#define FEXP2(x) exp2f(x)
#endif
#if __has_builtin(__builtin_amdgcn_logf)
#define FLOG2(x) __builtin_amdgcn_logf(x)   // v_log_f32 = log2
#else
#define FLOG2(x) __log2f(x)
#endif

// Relaxed agent-scope 64-bit atomics: plain coherence-point accesses, NO cache
// flushes (acquire/release at agent scope emit buffer_inv/buffer_wbl2 — the R2
// disaster). 64-bit units carry (tag<<32)|value so publication is in-band.
__device__ __forceinline__ ull aload64(const ull* p) {
  return __hip_atomic_load(p, __ATOMIC_RELAXED, __HIP_MEMORY_SCOPE_AGENT);
}
__device__ __forceinline__ void astore64(ull* p, ull x) {
  __hip_atomic_store(p, x, __ATOMIC_RELAXED, __HIP_MEMORY_SCOPE_AGENT);
}

// Pull one producer slice (RPB=375 tagged ulls) into LDS. Batched first
// attempt (6 independent loads in one MALL latency window), re-poll stragglers.
__device__ __forceinline__ void pull_tagged(const ull* __restrict__ src, int tag,
                                            float* __restrict__ dst, int lane) {
  const int nfull = RPB - 5 * 64;             // 55: lanes < 55 own 6 elements
  unsigned pend = (lane < nfull) ? 0x3Fu : 0x1Fu;
  {
    ull x0 = aload64(&src[lane]);
    ull x1 = aload64(&src[lane + 64]);
    ull x2 = aload64(&src[lane + 128]);
    ull x3 = aload64(&src[lane + 192]);
    ull x4 = aload64(&src[lane + 256]);
    ull x5 = (lane < nfull) ? aload64(&src[lane + 320]) : 0;
    if ((int)(x0 >> 32) == tag) { dst[lane]       = __uint_as_float((unsigned)x0); pend &= ~1u;  }
    if ((int)(x1 >> 32) == tag) { dst[lane + 64]  = __uint_as_float((unsigned)x1); pend &= ~2u;  }
    if ((int)(x2 >> 32) == tag) { dst[lane + 128] = __uint_as_float((unsigned)x2); pend &= ~4u;  }
    if ((int)(x3 >> 32) == tag) { dst[lane + 192] = __uint_as_float((unsigned)x3); pend &= ~8u;  }
    if ((int)(x4 >> 32) == tag) { dst[lane + 256] = __uint_as_float((unsigned)x4); pend &= ~16u; }
    if ((lane < nfull) && (int)(x5 >> 32) == tag) { dst[lane + 320] = __uint_as_float((unsigned)x5); pend &= ~32u; }
  }
  while (pend) {
    __builtin_amdgcn_s_sleep(1);
#pragma unroll
    for (int j = 0; j < 6; ++j) {
      if (!((pend >> j) & 1u)) continue;
      ull x = aload64(&src[lane + 64 * j]);
      if ((int)(x >> 32) == tag) {
        dst[lane + 64 * j] = __uint_as_float((unsigned)x);
        pend &= ~(1u << j);
      }
    }
  }
}

// ---------------------------------------------------------------------------
// K1: row L2 norms (as inverse) + top-8 smallest per row, VALUES kept.
// 8 rows/block, 32 lanes/row; register top-8 + 5-round shfl_xor bitonic merge.
// rowsel[t] = int2(m, raw C bits)  -> fill never re-reads C.
// ---------------------------------------------------------------------------
__global__ __launch_bounds__(256) void k_rowprep(const float* __restrict__ C,
                                                 float* __restrict__ invnorms,
                                                 int2* __restrict__ rowsel) {
  const int bn = blockIdx.x * 8 + (threadIdx.x >> 5);   // row id, 8 per block
  const int l  = threadIdx.x & 31;
  const float4* row4 = reinterpret_cast<const float4*>(C + (size_t)bn * NM);

  float tv[8]; int ti[8];
#pragma unroll
  for (int q = 0; q < 8; ++q) { tv[q] = FLT_MAX; ti[q] = 0x7fffffff; }
  float sq = 0.f;
  for (int c = 0; c < 24; ++c) {              // 750 float4 / 32 lanes
    int i = l + 32 * c;
    if (i < NM / 4) {
      float4 f = row4[i];
      sq += f.x * f.x + f.y * f.y + f.z * f.z + f.w * f.w;
      float e[4] = { f.x, f.y, f.z, f.w };
#pragma unroll
      for (int j = 0; j < 4; ++j) {
        float v = e[j];
        if (v < tv[7]) {                      // stable: strict <, asc indices
          int idx = 4 * i + j;
          int pos = 8;
#pragma unroll
          for (int q = 7; q >= 0; --q) if (v < tv[q]) pos = q;
#pragma unroll
          for (int q = 7; q >= 1; --q) if (q > pos) { tv[q] = tv[q-1]; ti[q] = ti[q-1]; }
#pragma unroll
          for (int q = 0; q < 8; ++q) if (q == pos) { tv[q] = v; ti[q] = idx; }
        }
      }
    }
  }
#pragma unroll
  for (int o = 16; o; o >>= 1) sq += __shfl_down(sq, o, 32);

#pragma unroll
  for (int msk = 1; msk <= 16; msk <<= 1) {
    float pv[8]; int pi[8];
#pragma unroll
    for (int q = 0; q < 8; ++q) { pv[q] = __shfl_xor(tv[q], msk); pi[q] = __shfl_xor(ti[q], msk); }
    float mv[8]; int mi[8];
#pragma unroll
    for (int q = 0; q < 8; ++q) {             // min with reversed partner
      float av = tv[q], bv = pv[7 - q];
      int   ai = ti[q], bi = pi[7 - q];
      bool ta = (av < bv) || (av == bv && ai < bi);
      mv[q] = ta ? av : bv; mi[q] = ta ? ai : bi;
    }
    auto ce = [&](int i, int j) {             // compare-exchange (val,idx) lex
      bool sw = (mv[i] > mv[j]) || (mv[i] == mv[j] && mi[i] > mi[j]);
      float fv = sw ? mv[j] : mv[i], gv = sw ? mv[i] : mv[j];
      int   fi = sw ? mi[j] : mi[i], gi = sw ? mi[i] : mi[j];
      mv[i] = fv; mv[j] = gv; mi[i] = fi; mi[j] = gi;
    };
    ce(0,4); ce(1,5); ce(2,6); ce(3,7);       // bitonic 3-stage cleaner
    ce(0,2); ce(1,3); ce(4,6); ce(5,7);
    ce(0,1); ce(2,3); ce(4,5); ce(6,7);
#pragma unroll
    for (int q = 0; q < 8; ++q) { tv[q] = mv[q]; ti[q] = mi[q]; }
  }

  if (l == 0) {
#pragma unroll
    for (int q = 0; q < 8; ++q)
      rowsel[(size_t)bn * KK + q] = make_int2(ti[q], __float_as_int(tv[q]));
    float nm = sqrtf(sq);
    invnorms[bn] = 1.0f / fmaxf(nm, 1e-12f);
  }
}

// ---------------------------------------------------------------------------
// K2a: column top-8, phase 1. NO LDS, no syncthreads: each wave owns one
// ~94-row chunk; lane owns 4 columns via float4 (1 KB/row/wave contiguous).
// key = (valbits<<32) | ~n : single u64 compare == (val desc, n asc).
// ---------------------------------------------------------------------------
__global__ __launch_bounds__(256) void k_coltop1(const float* __restrict__ C,
                                                 const float* __restrict__ invnorms,
                                                 ull* __restrict__ partial) {
  const int b = blockIdx.z, rc = blockIdx.y, cg = blockIdx.x;
  const int tid = threadIdx.x;
  const int w = tid >> 6, l = tid & 63;
  const int g4 = cg * 64 + l;                 // float4 group, valid < 750
  const int chunk = rc * 4 + w;               // 0..31

  ull tv[4][8];
#pragma unroll
  for (int j = 0; j < 4; ++j)
#pragma unroll
    for (int q = 0; q < 8; ++q) tv[j][q] = 0;   // real keys always > 0

  if (g4 < NM / 4) {
    const int base_r = rc * 375;
    const int r0 = base_r + w * 94;
    const int r1 = min(base_r + 375, r0 + 94);
    const float4* base = reinterpret_cast<const float4*>(
        C + (size_t)b * NN * NM) + g4;
    const float* ivn = invnorms + (size_t)b * NN;
    for (int n = r0; n < r1; ++n) {
      float4 f = base[(size_t)n * (NM / 4)];
      float iv = ivn[n];                      // wave-uniform -> scalar load
      float e[4] = { f.x * iv, f.y * iv, f.z * iv, f.w * iv };
      ull lo = (ull)(unsigned)~n;
#pragma unroll
      for (int j = 0; j < 4; ++j) {
        ull key = ((ull)__float_as_uint(e[j]) << 32) | lo;
        if (key > tv[j][7]) {
          int pos = 8;
#pragma unroll
          for (int q = 7; q >= 0; --q) if (key > tv[j][q]) pos = q;
#pragma unroll
          for (int q = 7; q >= 1; --q) if (q > pos) tv[j][q] = tv[j][q-1];
#pragma unroll
          for (int q = 0; q < 8; ++q) if (q == pos) tv[j][q] = key;
        }
      }
    }
    ull* dst = partial + (((size_t)b * NCH + chunk) * NM + (size_t)4 * g4) * 8;
#pragma unroll
    for (int j = 0; j < 4; ++j)
#pragma unroll
      for (int q = 0; q < 8; ++q) dst[j * 8 + q] = tv[j][q];
  }
}

// ---------------------------------------------------------------------------
// K2b: column top-8, phase 2. 64-thread blocks (375 blocks) so the 49 MB
// HBM-resident partial stream gets enough memory-level parallelism.
// ---------------------------------------------------------------------------
__global__ __launch_bounds__(64) void k_coltop2(const ull* __restrict__ partial,
                                                int2* __restrict__ colsel) {
  int t = blockIdx.x * 64 + threadIdx.x;      // b*NM + m
  if (t >= NB * NM) return;
  int b = t / NM, m = t % NM;
  ull top[8];
#pragma unroll
  for (int q = 0; q < 8; ++q) top[q] = 0;
  for (int c = 0; c < NCH; ++c) {
    const ull* src = partial + (((size_t)b * NCH + c) * NM + m) * 8;
    ull buf[8];
#pragma unroll
    for (int q = 0; q < 8; ++q) buf[q] = src[q];
    for (int q = 0; q < 8; ++q) {
      ull key = buf[q];
      if (key <= top[7]) break;               // list sorted desc -> rest smaller
      int pos = 8;
#pragma unroll
      for (int z = 7; z >= 0; --z) if (key > top[z]) pos = z;
#pragma unroll
      for (int z = 7; z >= 1; --z) if (z > pos) top[z] = top[z-1];
#pragma unroll
      for (int z = 0; z < 8; ++z) if (z == pos) top[z] = key;
    }
  }
#pragma unroll
  for (int q = 0; q < 8; ++q)
    colsel[(size_t)t * KK + q] =
        make_int2((int)~(unsigned)top[q], (int)(top[q] >> 32));
}

// ---------------------------------------------------------------------------
// K3 (fill): ZERO C reads — values come from rowsel/colsel. Base slots 0..7
// + non-duplicate extras (8+). pk arrays pre-filled with DUMMY_PAT.
// ---------------------------------------------------------------------------
__global__ __launch_bounds__(256) void k_fill(const float* __restrict__ invnorms,
    const int2* __restrict__ rowsel, const int2* __restrict__ colsel,
    int* r_cnt, int* c_cnt, int2* __restrict__ r_pk, int2* __restrict__ c_pk) {
  int t = blockIdx.x * 256 + threadIdx.x;
  if (t >= NB * NN * KK) return;
  int k = t % KK; int bn = t / KK;
  int b = bn / NN; int n = bn % NN;
  float inv_bn = invnorms[bn];
  int2 rs = rowsel[t];                        // (m, raw C bits)
  int2 cs = colsel[t];                        // (n2, (C*inv) bits)
  {  // base row entry
    float v2 = __int_as_float(rs.y) * inv_bn * SCALE;
    r_pk[(size_t)bn * CAP + k] = make_int2(rs.x, __float_as_int(v2));
  }
  {  // base col entry (bn reinterpreted as b*NM+m)
    float v2 = __int_as_float(cs.y) * SCALE;
    c_pk[(size_t)bn * CAP + k] = make_int2(cs.x, __float_as_int(v2));
  }
  int m = n;                                  // extras: t = (b*NM+m)*KK + k
  {  // colsel entry (b,m,k): row n3 gains column m unless duplicate
    int n3 = cs.x;
    const int2* rl = rowsel + ((size_t)b * NN + n3) * KK;
    bool dup = false;
#pragma unroll
    for (int q = 0; q < KK; ++q) dup |= (rl[q].x == m);
    if (!dup) {
      int slot = 8 + atomicAdd(&r_cnt[(size_t)b * NN + n3], 1);
      if (slot < CAP) {
        float v2 = __int_as_float(cs.y) * SCALE;
        r_pk[((size_t)b * NN + n3) * CAP + slot] = make_int2(m, __float_as_int(v2));
      }
    }
  }
  {  // rowsel entry (b,n,k): column mm gains row n unless duplicate
    int mm = rs.x;
    const int2* cl = colsel + ((size_t)b * NM + mm) * KK;
    bool dup = false;
#pragma unroll
    for (int q = 0; q < KK; ++q) dup |= (cl[q].x == n);
    if (!dup) {
      int slot = 8 + atomicAdd(&c_cnt[(size_t)b * NM + mm], 1);
      if (slot < CAP) {
        float v2 = __int_as_float(rs.y) * inv_bn * SCALE;
        c_pk[((size_t)b * NM + mm) * CAP + slot] = make_int2(n, __float_as_int(v2));
      }
    }
  }
}

// ---------------------------------------------------------------------------
// K5: tagged pull-as-ready sparse Sinkhorn (R9/R10/R12-validated, BPB=8
// TPB=512). Values published as (tag<<32)|bits via relaxed 64-bit agent
// atomics into parity buffers; consumers poll the data itself. Own slice
// registers->LDS. Reuse-distance-2 => pollers only ever see stale tags.
// ---------------------------------------------------------------------------
__global__ __launch_bounds__(TPB, 1) void k_sink_coop(
    const float* __restrict__ mu, const float* __restrict__ nu,
    const int2* __restrict__ r_pk, const int2* __restrict__ c_pk,
    ull* __restrict__ Upub, ull* __restrict__ Vpub,
    ull* errW, float* __restrict__ costpart) {
  const int blk = blockIdx.x;
  const int b = blk % NB, slice = blk / NB;
  const int tid = threadIdx.x;
  const int w = tid >> 6, lane = tid & 63;
  const int r = slice * RPB + tid;
  const bool has_r = (tid < RPB);             // NN == NM: same geometry

  // wave-resident sparse entries (persistent VGPRs; 124 VGPR total, no spill)
  float rval[CAP], cval[CAP];
  unsigned ridx[CAP / 2], cidx[CAP / 2];
  float u = 0.f, vv = 0.f, lmu = 0.f, lnu = 0.f;
  if (has_r) {
    const int2* rp = r_pk + ((size_t)b * NN + r) * CAP;
    const int2* cp = c_pk + ((size_t)b * NM + r) * CAP;
#pragma unroll
    for (int i = 0; i < CAP; i += 2) {
      int2 e0 = rp[i], e1 = rp[i + 1];
      rval[i] = __int_as_float(e0.y); rval[i + 1] = __int_as_float(e1.y);
      unsigned i0 = min((unsigned)e0.x & 0xFFFFu, (unsigned)(NN - 1));  // clamp dummies
      unsigned i1 = min((unsigned)e1.x & 0xFFFFu, (unsigned)(NN - 1));
      ridx[i / 2] = i0 | (i1 << 16);
      int2 f0 = cp[i], f1 = cp[i + 1];
      cval[i] = __int_as_float(f0.y); cval[i + 1] = __int_as_float(f1.y);
      unsigned j0 = min((unsigned)f0.x & 0xFFFFu, (unsigned)(NN - 1));
      unsigned j1 = min((unsigned)f1.x & 0xFFFFu, (unsigned)(NN - 1));
      cidx[i / 2] = j0 | (j1 << 16);
    }
    lmu = FLOG2(mu[(size_t)b * NN + r] + 1e-8f);
    lnu = FLOG2(nu[(size_t)b * NM + r] + 1e-8f);
  }

  __shared__ float XL[NN];                    // staged U or V (12 KB)
  __shared__ float sred[TPB / 64];
  __shared__ float errl[BPB];
  int itf = 0;
  bool done = false;

  for (int it = 0; it < 100; ++it) {
    // ---- stage-A: XL <- V(it-1) (zeros at it==0); own slice from registers ----
    if (it == 0) {
      for (int i = tid; i < NN; i += TPB) XL[i] = 0.f;
    } else {
      if (has_r) XL[r] = vv;
      if (w != slice) {
        const ull* src = Vpub + (size_t)((it - 1) & 1) * (NB * NN)
                       + (size_t)b * NN + (size_t)w * RPB;
        pull_tagged(src, it, XL + w * RPB, lane);
      }
    }
    __syncthreads();

    // ---- compute-A: u update, publish tagged U ----
    float errp = 0.f;
    if (has_r) {
      float s = 0.f;
#pragma unroll
      for (int i = 0; i < CAP; ++i) {
        int ix = (ridx[i >> 1] >> ((i & 1) * 16)) & 0xFFFF;
        s += FEXP2(u + XL[ix] - rval[i]);
      }
      float un = lmu - FLOG2(1e-8f + s) + u;
      errp = fabsf(un - u);
      u = un;
      astore64(&Upub[(size_t)(it & 1) * (NB * NN) + (size_t)b * NN + r],
               ((ull)(unsigned)(it + 1) << 32) | __float_as_uint(u));
    }
#pragma unroll
    for (int o = 32; o; o >>= 1) errp += __shfl_down(errp, o);
    if (lane == 0) sred[w] = errp;
    __syncthreads();                          // also: XL(V) reads done -> safe to overwrite
    if (tid == 0) {
      float e = sred[0] + sred[1] + sred[2] + sred[3]
              + sred[4] + sred[5] + sred[6] + sred[7];
      astore64(&errW[(size_t)((it & 1) * NB + b) * BPB * 16 + slice * 16],
               ((ull)(unsigned)(it + 1) << 32) | __float_as_uint(e));
      errl[slice] = e;
    }

    // ---- stage-B: XL <- U(it); own slice from registers; err words ----
    if (has_r) XL[r] = u;
    if (w != slice) {
      const ull* src = Upub + (size_t)(it & 1) * (NB * NN)
                     + (size_t)b * NN + (size_t)w * RPB;
      pull_tagged(src, it + 1, XL + w * RPB, lane);
      if (lane == 0) {
        const ull* ep = errW + (size_t)((it & 1) * NB + b) * BPB * 16 + w * 16;
        ull x = aload64(ep);
        while ((int)(x >> 32) != it + 1) { __builtin_amdgcn_s_sleep(1); x = aload64(ep); }
        errl[w] = __uint_as_float((unsigned)x);
      }
    }
    __syncthreads();

    // ---- compute-B: uniform done decision, v update, publish tagged V ----
    float errtot = errl[0] + errl[1] + errl[2] + errl[3]
                 + errl[4] + errl[5] + errl[6] + errl[7];   // fixed order
    done = (errtot * UNSCALE < THRESH);
    if (has_r) {
      float s = 0.f;
#pragma unroll
      for (int i = 0; i < CAP; ++i) {
        int ix = (cidx[i >> 1] >> ((i & 1) * 16)) & 0xFFFF;
        s += FEXP2(vv + XL[ix] - cval[i]);
      }
      vv = lnu - FLOG2(1e-8f + s) + vv;
      astore64(&Vpub[(size_t)(it & 1) * (NB * NN) + (size_t)b * NN + r],
               ((ull)(unsigned)(it + 1) << 32) | __float_as_uint(vv));
    }
    __syncthreads();                          // XL(U) reads done -> next overwrite safe
    itf = it;
    if (done) break;                          // uniform across the batch
  }

  // ---- epilogue: XL <- V(itf); cost partial over own rows ----
  if (has_r) XL[r] = vv;
  if (w != slice) {
    const ull* src = Vpub + (size_t)(itf & 1) * (NB * NN)
                   + (size_t)b * NN + (size_t)w * RPB;
    pull_tagged(src, itf + 1, XL + w * RPB, lane);
  }
  __syncthreads();
  float cs = 0.f;
  if (has_r) {
#pragma unroll
    for (int i = 0; i < CAP; ++i) {
      int ix = (ridx[i >> 1] >> ((i & 1) * 16)) & 0xFFFF;
      float val = rval[i];
      cs += FEXP2(u + XL[ix] - val) * val;    // dummies give exp2(-huge)*big = 0
    }
  }
#pragma unroll
  for (int o = 32; o; o >>= 1) cs += __shfl_down(cs, o);
  if (lane == 0) sred[w] = cs;
  __syncthreads();
  if (tid == 0)
    costpart[b * BPB + slice] = sred[0] + sred[1] + sred[2] + sred[3]
                              + sred[4] + sred[5] + sred[6] + sred[7];
}

// Deterministic final reduction: fixed-order sums.
__global__ void k_final2(const float* __restrict__ costpart, float* __restrict__ out) {
  if (threadIdx.x == 0 && blockIdx.x == 0) {
    float tot = 0.f;
    for (int b = 0; b < NB; ++b) {
      float cb = 0.f;
      for (int s = 0; s < BPB; ++s) cb += costpart[b * BPB + s];
      tot += cb * UNSCALE;
    }
    out[0] = tot * (1.0f / NB);
  }
}

// ---------------------------------------------------------------------------
extern "C" void kernel_launch(void* const* d_in, const int* in_sizes, int n_in,
                              void* d_out, int out_size, void* d_ws, size_t ws_size,
                              hipStream_t stream) {
  const float* mu = (const float*)d_in[0];
  const float* nu = (const float*)d_in[1];
  const float* C  = (const float*)d_in[2];
  float* out = (float*)d_out;

  char* ws = (char*)d_ws;
  size_t off = 0;
  auto alloc = [&](size_t bytes) {
    void* p = ws + off;
    off += (bytes + 255) & ~(size_t)255;
    return p;
  };
  float* invnorms = (float*)alloc(sizeof(float) * NB * NN);
  int2*  rowsel   = (int2*) alloc(sizeof(int2)  * NB * NN * KK);     // (m, raw bits)
  int2*  colsel   = (int2*) alloc(sizeof(int2)  * NB * NM * KK);     // (n, scaled bits)
  ull*   partial  = (ull*)  alloc(sizeof(ull)   * NB * NCH * NM * 8); // 49 MB
  int2*  r_pk     = (int2*) alloc(sizeof(int2)  * NB * NN * CAP);
  int2*  c_pk     = (int2*) alloc(sizeof(int2)  * NB * NM * CAP);    // contiguous after r_pk
  // ---- zeroed region starts here (tags must reset every launch/replay) ----
  ull*   Upub     = (ull*)  alloc(sizeof(ull)   * 2 * NB * NN);      // tagged parity dbuf
  ull*   Vpub     = (ull*)  alloc(sizeof(ull)   * 2 * NB * NM);
  ull*   errW     = (ull*)  alloc(sizeof(ull)   * 2 * NB * BPB * 16);
  int*   r_cnt    = (int*)  alloc(sizeof(int)   * NB * NN);
  int*   c_cnt    = (int*)  alloc(sizeof(int)   * NB * NM);
  float* costpart = (float*)alloc(sizeof(float) * NB * BPB);
  (void)ws_size; (void)in_sizes; (void)n_in; (void)out_size;

  // pk arrays pre-filled with dummy pattern (val=3.39e38, idx clamped in sink)
  hipMemsetD32Async((hipDeviceptr_t)r_pk, (int)DUMMY_PAT,
                    (size_t)2 * NB * NN * CAP * 2, stream);
  size_t span = (size_t)((char*)costpart - (char*)Upub)
              + ((sizeof(float) * NB * BPB + 255) & ~(size_t)255);
  hipMemsetAsync(Upub, 0, span, stream);      // Upub..costpart (tags -> 0)

  hipLaunchKernelGGL(k_rowprep, dim3(NB * NN / 8), dim3(256), 0, stream,
                     C, invnorms, rowsel);
  hipLaunchKernelGGL(k_coltop1, dim3(12, NCH / 4, NB), dim3(256), 0, stream,
                     C, invnorms, partial);
  hipLaunchKernelGGL(k_coltop2, dim3((NB * NM + 63) / 64), dim3(64), 0, stream,
                     partial, colsel);
  int nthreads = NB * NN * KK;
  hipLaunchKernelGGL(k_fill, dim3((nthreads + 255) / 256), dim3(256), 0, stream,
                     invnorms, rowsel, colsel, r_cnt, c_cnt, r_pk, c_pk);

  void* args[] = { (void*)&mu, (void*)&nu, (void*)&r_pk, (void*)&c_pk,
                   (void*)&Upub, (void*)&Vpub, (void*)&errW, (void*)&costpart };
  hipLaunchCooperativeKernel((const void*)k_sink_coop, dim3(NBLK), dim3(TPB),
                             args, 0, stream);

  hipLaunchKernelGGL(k_final2, dim3(1), dim3(64), 0, stream, costpart, out);
}